// Round 1
// baseline (7660.425 us; speedup 1.0000x reference)
//
#include <hip/hip_runtime.h>

#define NBLK_STATS 256

// ---------------- column stats (mean/var over axis 0), partial pass ----------------
template<int C, bool GATHER>
__global__ __launch_bounds__(256) void colstats_partial(
    const float* __restrict__ x,
    const float* __restrict__ xu, const float* __restrict__ xv,
    const int* __restrict__ gsrc, const int* __restrict__ gdst,
    int M, float* __restrict__ psum, float* __restrict__ psq)
{
    constexpr int SUBS = 256 / C;   // 2 for C=128, 1 for C=256
    const int c   = threadIdx.x % C;
    const int sub = threadIdx.x / C;
    float s = 0.f, q = 0.f;
    for (int r = blockIdx.x * SUBS + sub; r < M; r += gridDim.x * SUBS) {
        float v;
        if constexpr (GATHER) {
            int su = gsrc[r], sv = gdst[r];
            v = xu[(size_t)su * 128 + c] + xv[(size_t)sv * 128 + c];
        } else {
            v = x[(size_t)r * C + c];
        }
        s += v; q += v * v;
    }
    if constexpr (SUBS > 1) {
        __shared__ float ss[256], qs[256];
        ss[threadIdx.x] = s; qs[threadIdx.x] = q;
        __syncthreads();
        if (sub == 0) { s += ss[threadIdx.x + C]; q += qs[threadIdx.x + C]; }
    }
    if (sub == 0) {
        psum[blockIdx.x * C + c] = s;
        psq [blockIdx.x * C + c] = q;
    }
}

__global__ void colstats_final(const float* __restrict__ psum, const float* __restrict__ psq,
                               int C, int M, float* __restrict__ mean, float* __restrict__ rstd)
{
    int c = threadIdx.x;
    if (c >= C) return;
    double s = 0.0, q = 0.0;
    for (int i = 0; i < NBLK_STATS; ++i) {
        s += (double)psum[(size_t)i * C + c];
        q += (double)psq [(size_t)i * C + c];
    }
    double m = s / M;
    double v = q / M - m * m;
    if (v < 0.0) v = 0.0;
    mean[c] = (float)m;
    rstd[c] = (float)(1.0 / sqrt(v + 1e-5));
}

// ---------------- fold BN into GEMM weights ----------------
// W_eff[c,d] = rstd[c]*g[c]*W[c,d] ; b_eff[d] = bias[d] + sum_c (b[c]-mean[c]*rstd[c]*g[c])*W[c,d]
__global__ __launch_bounds__(256) void fold_params(
    const float* __restrict__ W, const float* __restrict__ bias,
    const float* __restrict__ g, const float* __restrict__ b,
    const float* __restrict__ mean, const float* __restrict__ rstd,
    int C, float* __restrict__ Weff, float* __restrict__ beff)
{
    int d = threadIdx.x & 127;
    int half = threadIdx.x >> 7;
    float acc = 0.f;
    for (int c = half; c < C; c += 2) {
        float a = rstd[c] * g[c];
        float w = W[(size_t)c * 128 + d];
        Weff[(size_t)c * 128 + d] = w * a;
        acc += (b[c] - mean[c] * a) * w;
    }
    __shared__ float red[256];
    red[threadIdx.x] = acc;
    __syncthreads();
    if (half == 0) beff[d] = bias[d] + red[d] + red[d + 128];
}

// ---------------- fused (gather?) -> GEMM+bias+ReLU -> (scatter-add?) ----------------
// A is [M,C] (or gathered hu[src]+hv[dst], C=128). W_eff [C,128]. Out: store Y or atomicAdd into SUMBUF by gdst.
template<int C, bool GATHER, bool SCATTER>
__global__ __launch_bounds__(256) void gemm_block(
    const float* __restrict__ A,
    const float* __restrict__ XU, const float* __restrict__ XV,
    const int* __restrict__ gsrc, const int* __restrict__ gdst,
    const float* __restrict__ Wf, const float* __restrict__ bf,
    float* __restrict__ Y, float* __restrict__ SUMBUF, int M)
{
    constexpr int KC = 16;
    __shared__ __align__(16) float As[KC][132];
    __shared__ __align__(16) float Ws[KC][132];
    const int tid = threadIdx.x;
    const int rb  = blockIdx.x * 128;
    const int tx = tid & 15;        // 16 col groups (cols tx*4 and 64+tx*4)
    const int ty = tid >> 4;        // 16 row groups (rows ty*8..ty*8+7)
    const int lrow  = tid >> 1;     // 0..127 staging row
    const int khalf = (tid & 1) * 8;
    const int grow = rb + lrow;
    const bool rowok = (grow < M);

    const float* ArowU = nullptr; const float* ArowV = nullptr; const float* Arow = nullptr;
    if constexpr (GATHER) {
        int su = 0, sv = 0;
        if (rowok) { su = gsrc[grow]; sv = gdst[grow]; }
        ArowU = XU + (size_t)su * 128;
        ArowV = XV + (size_t)sv * 128;
    } else {
        Arow = A + (size_t)grow * C;
    }

    float acc[8][8] = {};

    for (int k0 = 0; k0 < C; k0 += KC) {
        float4 a0 = make_float4(0.f,0.f,0.f,0.f), a1 = a0;
        if (rowok) {
            if constexpr (GATHER) {
                float4 u0 = *(const float4*)(ArowU + k0 + khalf);
                float4 u1 = *(const float4*)(ArowU + k0 + khalf + 4);
                float4 v0 = *(const float4*)(ArowV + k0 + khalf);
                float4 v1 = *(const float4*)(ArowV + k0 + khalf + 4);
                a0 = make_float4(u0.x+v0.x, u0.y+v0.y, u0.z+v0.z, u0.w+v0.w);
                a1 = make_float4(u1.x+v1.x, u1.y+v1.y, u1.z+v1.z, u1.w+v1.w);
            } else {
                a0 = *(const float4*)(Arow + k0 + khalf);
                a1 = *(const float4*)(Arow + k0 + khalf + 4);
            }
        }
        const float4 w0 = *(const float4*)(Wf + (size_t)k0 * 128 + tid * 4);
        const float4 w1 = *(const float4*)(Wf + (size_t)k0 * 128 + 1024 + tid * 4);
        __syncthreads();
        As[khalf+0][lrow] = a0.x; As[khalf+1][lrow] = a0.y;
        As[khalf+2][lrow] = a0.z; As[khalf+3][lrow] = a0.w;
        As[khalf+4][lrow] = a1.x; As[khalf+5][lrow] = a1.y;
        As[khalf+6][lrow] = a1.z; As[khalf+7][lrow] = a1.w;
        {
            int f0 = tid * 4;
            *(float4*)&Ws[f0 >> 7][f0 & 127] = w0;
            int f1 = 1024 + tid * 4;
            *(float4*)&Ws[f1 >> 7][f1 & 127] = w1;
        }
        __syncthreads();
        #pragma unroll
        for (int kk = 0; kk < KC; ++kk) {
            const float4 av0 = *(const float4*)&As[kk][ty * 8];
            const float4 av1 = *(const float4*)&As[kk][ty * 8 + 4];
            const float4 wv0 = *(const float4*)&Ws[kk][tx * 4];
            const float4 wv1 = *(const float4*)&Ws[kk][64 + tx * 4];
            float a[8] = {av0.x,av0.y,av0.z,av0.w,av1.x,av1.y,av1.z,av1.w};
            float w[8] = {wv0.x,wv0.y,wv0.z,wv0.w,wv1.x,wv1.y,wv1.z,wv1.w};
            #pragma unroll
            for (int i = 0; i < 8; ++i)
                #pragma unroll
                for (int j = 0; j < 8; ++j)
                    acc[i][j] += a[i] * w[j];
        }
    }

    float bz[8];
    #pragma unroll
    for (int j = 0; j < 4; ++j) { bz[j] = bf[tx*4 + j]; bz[4+j] = bf[64 + tx*4 + j]; }
    #pragma unroll
    for (int i = 0; i < 8; ++i) {
        int r = rb + ty * 8 + i;
        if (r < M) {
            float o[8];
            #pragma unroll
            for (int j = 0; j < 8; ++j) o[j] = fmaxf(acc[i][j] + bz[j], 0.f);
            if constexpr (SCATTER) {
                int dn = gdst[r];
                float* p = SUMBUF + (size_t)dn * 128;
                #pragma unroll
                for (int j = 0; j < 4; ++j) atomicAdd(p + tx*4 + j, o[j]);
                #pragma unroll
                for (int j = 0; j < 4; ++j) atomicAdd(p + 64 + tx*4 + j, o[4+j]);
            } else {
                float4 o0 = make_float4(o[0],o[1],o[2],o[3]);
                float4 o1 = make_float4(o[4],o[5],o[6],o[7]);
                *(float4*)(Y + (size_t)r * 128 + tx*4) = o0;
                *(float4*)(Y + (size_t)r * 128 + 64 + tx*4) = o1;
            }
        }
    }
}

// ---------------- misc small kernels ----------------
__global__ __launch_bounds__(256) void count_edges(const int* __restrict__ dst,
                                                   float* __restrict__ cnt, int E)
{
    for (int i = blockIdx.x * 256 + threadIdx.x; i < E; i += gridDim.x * 256)
        atomicAdd(&cnt[dst[i]], 1.0f);
}

__global__ __launch_bounds__(256) void finalize_h(
    const float* __restrict__ sw, const float* __restrict__ sl,
    const float* __restrict__ cw, const float* __restrict__ cl,
    float* __restrict__ h, float* __restrict__ fhhalf, int N)
{
    const int total = N * 128;
    for (int i = blockIdx.x * 256 + threadIdx.x; i < total; i += gridDim.x * 256) {
        int n = i >> 7, c = i & 127;
        float v = 0.5f * (sw[i] / fmaxf(cw[n], 1.f) + sl[i] / fmaxf(cl[n], 1.f));
        h[i] = v;
        if (fhhalf) fhhalf[((size_t)n << 8) + c] = v;
    }
}

// ---------------- launch ----------------
extern "C" void kernel_launch(void* const* d_in, const int* in_sizes, int n_in,
                              void* d_out, int out_size, void* d_ws, size_t ws_size,
                              hipStream_t stream)
{
    const float* win_f  = (const float*)d_in[0];
    const float* loss_f = (const float*)d_in[1];
    struct BP { const float *g, *b, *W, *bias; };
    auto bp = [&](int i) { return BP{ (const float*)d_in[i], (const float*)d_in[i+1],
                                      (const float*)d_in[i+2], (const float*)d_in[i+3] }; };
    BP wi = bp(2), li = bp(6), srcp = bp(10), dstp = bp(14), wl = bp(18), ll = bp(22), outp = bp(26);
    const int* win_src  = (const int*)d_in[30];
    const int* win_dst  = (const int*)d_in[31];
    const int* loss_src = (const int*)d_in[32];
    const int* loss_dst = (const int*)d_in[33];
    const int E = in_sizes[30];
    const int N = out_size / 128;
    (void)n_in;

    char* base = (char*)d_ws;
    size_t off = 0;
    auto alloc = [&](size_t bytes) {
        size_t cur = off;
        off += (bytes + 255) & ~(size_t)255;
        return (void*)(base + cur);
    };
    float* sum_w = (float*)alloc((size_t)N * 128 * 4);
    float* sum_l = (float*)alloc((size_t)N * 128 * 4);
    float* h     = (float*)alloc((size_t)N * 128 * 4);
    float* hu    = (float*)alloc((size_t)N * 128 * 4);
    float* hv    = (float*)alloc((size_t)N * 128 * 4);
    float* fh    = (float*)alloc((size_t)N * 256 * 4);
    float* cnt_w = (float*)alloc((size_t)N * 4);
    float* cnt_l = (float*)alloc((size_t)N * 4);
    float* psum  = (float*)alloc((size_t)NBLK_STATS * 256 * 4);
    float* psq   = (float*)alloc((size_t)NBLK_STATS * 256 * 4);
    float* mean  = (float*)alloc(256 * 4);
    float* rstd  = (float*)alloc(256 * 4);
    float* Weff  = (float*)alloc((size_t)256 * 128 * 4);
    float* beff  = (float*)alloc(128 * 4);
    if (off > ws_size) return;  // workspace too small: bail cleanly

    auto stats_x = [&](const float* x, int M, int C) {
        if (C == 128) colstats_partial<128,false><<<NBLK_STATS,256,0,stream>>>(x,nullptr,nullptr,nullptr,nullptr,M,psum,psq);
        else          colstats_partial<256,false><<<NBLK_STATS,256,0,stream>>>(x,nullptr,nullptr,nullptr,nullptr,M,psum,psq);
        colstats_final<<<1,256,0,stream>>>(psum,psq,C,M,mean,rstd);
    };
    auto stats_gather = [&](const float* u, const float* v, const int* s, const int* d, int M) {
        colstats_partial<128,true><<<NBLK_STATS,256,0,stream>>>(nullptr,u,v,s,d,M,psum,psq);
        colstats_final<<<1,256,0,stream>>>(psum,psq,128,M,mean,rstd);
    };
    auto fold = [&](const BP& p, int C) {
        fold_params<<<1,256,0,stream>>>(p.W,p.bias,p.g,p.b,mean,rstd,C,Weff,beff);
    };

    const int gE = (E + 127) / 128;
    const int gN = (N + 127) / 128;

    hipMemsetAsync(cnt_w, 0, (size_t)N * 4, stream);
    hipMemsetAsync(cnt_l, 0, (size_t)N * 4, stream);
    hipMemsetAsync(sum_w, 0, (size_t)N * 128 * 4, stream);
    hipMemsetAsync(sum_l, 0, (size_t)N * 128 * 4, stream);
    count_edges<<<1024,256,0,stream>>>(win_dst,  cnt_w, E);
    count_edges<<<1024,256,0,stream>>>(loss_dst, cnt_l, E);

    // initial edge blocks: block(win_f, wi) scattered into sum_w ; block(loss_f, li) -> sum_l
    stats_x(win_f, E, 128);
    fold(wi, 128);
    gemm_block<128,false,true><<<gE,256,0,stream>>>(win_f,nullptr,nullptr,nullptr,win_dst,Weff,beff,nullptr,sum_w,E);
    stats_x(loss_f, E, 128);
    fold(li, 128);
    gemm_block<128,false,true><<<gE,256,0,stream>>>(loss_f,nullptr,nullptr,nullptr,loss_dst,Weff,beff,nullptr,sum_l,E);
    finalize_h<<<1024,256,0,stream>>>(sum_w,sum_l,cnt_w,cnt_l,h,fh,N);  // fh left half = f

    for (int it = 0; it < 3; ++it) {
        stats_x(h, N, 128);               // shared stats for both hu and hv blocks
        fold(srcp, 128);
        gemm_block<128,false,false><<<gN,256,0,stream>>>(h,nullptr,nullptr,nullptr,nullptr,Weff,beff,hu,nullptr,N);
        fold(dstp, 128);
        gemm_block<128,false,false><<<gN,256,0,stream>>>(h,nullptr,nullptr,nullptr,nullptr,Weff,beff,hv,nullptr,N);

        stats_gather(hu,hv,win_src,win_dst,E);
        fold(wl, 128);
        hipMemsetAsync(sum_w, 0, (size_t)N * 128 * 4, stream);
        gemm_block<128,true,true><<<gE,256,0,stream>>>(nullptr,hu,hv,win_src,win_dst,Weff,beff,nullptr,sum_w,E);

        stats_gather(hu,hv,loss_src,loss_dst,E);
        fold(ll, 128);
        hipMemsetAsync(sum_l, 0, (size_t)N * 128 * 4, stream);
        gemm_block<128,true,true><<<gE,256,0,stream>>>(nullptr,hu,hv,loss_src,loss_dst,Weff,beff,nullptr,sum_l,E);

        finalize_h<<<1024,256,0,stream>>>(sum_w,sum_l,cnt_w,cnt_l,h,(it==2)?(fh+128):nullptr,N);
    }

    stats_x(fh, N, 256);
    fold(outp, 256);
    gemm_block<256,false,false><<<gN,256,0,stream>>>(fh,nullptr,nullptr,nullptr,nullptr,Weff,beff,(float*)d_out,nullptr,N);
}

// Round 2
// 3749.657 us; speedup vs baseline: 2.0430x; 2.0430x over previous
//
#include <hip/hip_runtime.h>

#define NBLK_STATS 256

typedef __attribute__((ext_vector_type(8))) short short8;
typedef __attribute__((ext_vector_type(4))) float f32x4;

__device__ __forceinline__ float bf2f(uint u) {
    union { uint u; float f; } v; v.u = u << 16; return v.f;
}
__device__ __forceinline__ ushort f2bf(float f) {
    union { float f; uint u; } v; v.f = f;
    uint r = v.u + 0x7fffu + ((v.u >> 16) & 1u);
    return (ushort)(r >> 16);
}

// ---------------- phase 0: counting sort by dst ----------------
__global__ __launch_bounds__(256) void hist_kernel(const int* __restrict__ dst, int E,
                                                   int* __restrict__ cnt) {
    for (int e = blockIdx.x * 256 + threadIdx.x; e < E; e += gridDim.x * 256)
        atomicAdd(&cnt[dst[e]], 1);
}

// single-block exclusive scan: off[0..n] and cursor copy
__global__ __launch_bounds__(256) void scan_kernel(const int* __restrict__ cnt, int n,
                                                   int* __restrict__ off, int* __restrict__ cursor) {
    __shared__ int warpsums[4];
    __shared__ int s_carry;
    if (threadIdx.x == 0) s_carry = 0;
    __syncthreads();
    for (int base = 0; base < n; base += 256) {
        int i = base + threadIdx.x;
        int v = (i < n) ? cnt[i] : 0;
        int lane = threadIdx.x & 63, w = threadIdx.x >> 6;
        int x = v;
        for (int d = 1; d < 64; d <<= 1) {
            int y = __shfl_up(x, d);
            if (lane >= d) x += y;
        }
        if (lane == 63) warpsums[w] = x;
        __syncthreads();
        int woff = 0;
        for (int k = 0; k < w; ++k) woff += warpsums[k];
        int incl = x + woff + s_carry;
        int excl = incl - v;
        if (i < n) { off[i] = excl; cursor[i] = excl; }
        __syncthreads();
        if (threadIdx.x == 255) s_carry = incl;
        __syncthreads();
    }
    if (threadIdx.x == 0) off[n] = s_carry;
}

__global__ __launch_bounds__(256) void scatter_kernel(const int* __restrict__ src,
                                                      const int* __restrict__ dst, int E,
                                                      int* __restrict__ cursor,
                                                      int* __restrict__ perm,
                                                      int* __restrict__ ssrc,
                                                      int* __restrict__ sdst) {
    for (int e = blockIdx.x * 256 + threadIdx.x; e < E; e += gridDim.x * 256) {
        int d = dst[e];
        int p = atomicAdd(&cursor[d], 1);
        perm[p] = e;
        ssrc[p] = src[e];
        sdst[p] = d;
    }
}

// ---------------- column stats partials ----------------
__global__ __launch_bounds__(256) void colstats_f32_128(const float* __restrict__ x, int M,
                                                        float* __restrict__ psum, float* __restrict__ psq) {
    int c = threadIdx.x & 127, sub = threadIdx.x >> 7;
    float s = 0.f, q = 0.f;
    for (int r = blockIdx.x * 2 + sub; r < M; r += gridDim.x * 2) {
        float v = x[(size_t)r * 128 + c];
        s += v; q += v * v;
    }
    __shared__ float ss[256], qs[256];
    ss[threadIdx.x] = s; qs[threadIdx.x] = q;
    __syncthreads();
    if (sub == 0) {
        s += ss[threadIdx.x + 128]; q += qs[threadIdx.x + 128];
        psum[blockIdx.x * 128 + c] = s;
        psq [blockIdx.x * 128 + c] = q;
    }
}

template<int C>
__global__ __launch_bounds__(256) void colstats_bf16_direct(const ushort* __restrict__ x, int M,
                                                            float* __restrict__ psum, float* __restrict__ psq) {
    if constexpr (C == 128) {
        int c = threadIdx.x & 127, sub = threadIdx.x >> 7;
        float s = 0.f, q = 0.f;
        for (int r = blockIdx.x * 2 + sub; r < M; r += gridDim.x * 2) {
            float v = bf2f(x[(size_t)r * 128 + c]);
            s += v; q += v * v;
        }
        __shared__ float ss[256], qs[256];
        ss[threadIdx.x] = s; qs[threadIdx.x] = q;
        __syncthreads();
        if (sub == 0) {
            s += ss[threadIdx.x + 128]; q += qs[threadIdx.x + 128];
            psum[blockIdx.x * 128 + c] = s;
            psq [blockIdx.x * 128 + c] = q;
        }
    } else {
        int c = threadIdx.x;
        float s = 0.f, q = 0.f;
        for (int r = blockIdx.x; r < M; r += gridDim.x) {
            float v = bf2f(x[(size_t)r * C + c]);
            s += v; q += v * v;
        }
        psum[blockIdx.x * C + c] = s;
        psq [blockIdx.x * C + c] = q;
    }
}

__global__ __launch_bounds__(256) void colstats_bf16_gather(const ushort* __restrict__ hu,
                                                            const ushort* __restrict__ hv,
                                                            const int* __restrict__ s_idx,
                                                            const int* __restrict__ d_idx, int M,
                                                            float* __restrict__ psum, float* __restrict__ psq) {
    int c = threadIdx.x & 127, sub = threadIdx.x >> 7;
    float s = 0.f, q = 0.f;
    for (int r = blockIdx.x * 2 + sub; r < M; r += gridDim.x * 2) {
        int a = s_idx[r], b = d_idx[r];
        float v = bf2f(hu[(size_t)a * 128 + c]) + bf2f(hv[(size_t)b * 128 + c]);
        s += v; q += v * v;
    }
    __shared__ float ss[256], qs[256];
    ss[threadIdx.x] = s; qs[threadIdx.x] = q;
    __syncthreads();
    if (sub == 0) {
        s += ss[threadIdx.x + 128]; q += qs[threadIdx.x + 128];
        psum[blockIdx.x * 128 + c] = s;
        psq [blockIdx.x * 128 + c] = q;
    }
}

// ---------------- stats finalize + BN fold + MFMA-fragment pack (single block) ----------------
// Wpack[((dt*KT + kt)*64 + lane)*8 + i] = bf16( Weff[kt*32 + (lane>>4)*8 + i][dt*16 + (lane&15)] )
__global__ __launch_bounds__(256) void finalize_fold(
    const float* __restrict__ psum, const float* __restrict__ psq, int M, int C,
    const float* __restrict__ W, const float* __restrict__ bias,
    const float* __restrict__ g, const float* __restrict__ b,
    ushort* __restrict__ Wp, float* __restrict__ beff) {
    __shared__ float sscale[256];   // rstd*g
    __shared__ float sshift[256];   // b - mean*rstd*g
    int c = threadIdx.x;
    if (c < C) {
        double s = 0.0, q = 0.0;
        for (int i = 0; i < NBLK_STATS; ++i) {
            s += (double)psum[(size_t)i * C + c];
            q += (double)psq [(size_t)i * C + c];
        }
        double m = s / M;
        double v = q / M - m * m;
        if (v < 0.0) v = 0.0;
        float rs = (float)(1.0 / sqrt(v + 1e-5));
        float sc = rs * g[c];
        sscale[c] = sc;
        sshift[c] = b[c] - (float)m * sc;
    }
    __syncthreads();
    const int KT = C / 32;
    const int total = 8 * KT * 64;
    for (int f = threadIdx.x; f < total; f += 256) {
        int lane = f & 63;
        int t = f >> 6;
        int kt = t % KT, dt = t / KT;
        int d = dt * 16 + (lane & 15);
        int kb = kt * 32 + (lane >> 4) * 8;
        uint4 o;
        uint w0, w1;
        w0 = (uint)f2bf(W[(size_t)(kb+0)*128 + d] * sscale[kb+0]);
        w1 = (uint)f2bf(W[(size_t)(kb+1)*128 + d] * sscale[kb+1]);
        o.x = w0 | (w1 << 16);
        w0 = (uint)f2bf(W[(size_t)(kb+2)*128 + d] * sscale[kb+2]);
        w1 = (uint)f2bf(W[(size_t)(kb+3)*128 + d] * sscale[kb+3]);
        o.y = w0 | (w1 << 16);
        w0 = (uint)f2bf(W[(size_t)(kb+4)*128 + d] * sscale[kb+4]);
        w1 = (uint)f2bf(W[(size_t)(kb+5)*128 + d] * sscale[kb+5]);
        o.z = w0 | (w1 << 16);
        w0 = (uint)f2bf(W[(size_t)(kb+6)*128 + d] * sscale[kb+6]);
        w1 = (uint)f2bf(W[(size_t)(kb+7)*128 + d] * sscale[kb+7]);
        o.w = w0 | (w1 << 16);
        *(uint4*)(Wp + (size_t)f * 8) = o;
    }
    if (threadIdx.x < 128) {
        int d = threadIdx.x;
        float a = bias[d];
        for (int cc = 0; cc < C; ++cc) a += sshift[cc] * W[(size_t)cc * 128 + d];
        beff[d] = a;
    }
}

// ---------------- MFMA GEMM: Y[row][d] = relu( X[row] @ Weff + beff ) ----------------
// A-operand = packed Weff^T fragments (per-lane 16B contiguous), B-operand = row fragments
// (per-lane 16B contiguous from the bf16 row). D: col=lane&15 -> row, row=(lane>>4)*4+j -> feature.
// TWO: row = hu[g1[row]] + hv[g2[row]] via two MFMAs (linearity).
template<int KT, bool TWO, bool PERMF32, bool OUTF32>
__global__ __launch_bounds__(256) void gemm_mfma(
    const ushort* __restrict__ X1, const ushort* __restrict__ X2,
    const float* __restrict__ XF,
    const int* __restrict__ g1, const int* __restrict__ g2,
    const ushort* __restrict__ Wp, const float* __restrict__ beff,
    ushort* __restrict__ Yb, float* __restrict__ Yf, int M) {
    constexpr int K = KT * 32;
    const int lane = threadIdx.x & 63;
    const int w = threadIdx.x >> 6;
    const int r0 = blockIdx.x * 128 + w * 32;
    const int rlo = lane & 15, khi = lane >> 4;

    f32x4 acc[2][8];
    #pragma unroll
    for (int rt = 0; rt < 2; ++rt)
        #pragma unroll
        for (int dt = 0; dt < 8; ++dt)
            acc[rt][dt] = (f32x4){0.f, 0.f, 0.f, 0.f};

    int row[2], idx1[2], idx2[2];
    bool ok[2];
    #pragma unroll
    for (int rt = 0; rt < 2; ++rt) {
        row[rt] = r0 + rt * 16 + rlo;
        ok[rt] = row[rt] < M;
        int rr = ok[rt] ? row[rt] : 0;
        idx1[rt] = g1 ? g1[rr] : rr;
        if constexpr (TWO) idx2[rt] = g2[rr];
    }

    for (int kt = 0; kt < KT; ++kt) {
        short8 wf[8];
        #pragma unroll
        for (int dt = 0; dt < 8; ++dt)
            wf[dt] = *(const short8*)(Wp + (size_t)((dt * KT + kt) * 64 + lane) * 8);
        #pragma unroll
        for (int rt = 0; rt < 2; ++rt) {
            short8 bv;
            if constexpr (PERMF32) {
                const float* p = XF + (size_t)idx1[rt] * K + kt * 32 + khi * 8;
                float4 xa = *(const float4*)(p);
                float4 xb = *(const float4*)(p + 4);
                bv[0] = (short)f2bf(xa.x); bv[1] = (short)f2bf(xa.y);
                bv[2] = (short)f2bf(xa.z); bv[3] = (short)f2bf(xa.w);
                bv[4] = (short)f2bf(xb.x); bv[5] = (short)f2bf(xb.y);
                bv[6] = (short)f2bf(xb.z); bv[7] = (short)f2bf(xb.w);
            } else {
                bv = *(const short8*)(X1 + (size_t)idx1[rt] * K + kt * 32 + khi * 8);
            }
            #pragma unroll
            for (int dt = 0; dt < 8; ++dt)
                acc[rt][dt] = __builtin_amdgcn_mfma_f32_16x16x32_bf16(wf[dt], bv, acc[rt][dt], 0, 0, 0);
            if constexpr (TWO) {
                short8 bv2 = *(const short8*)(X2 + (size_t)idx2[rt] * K + kt * 32 + khi * 8);
                #pragma unroll
                for (int dt = 0; dt < 8; ++dt)
                    acc[rt][dt] = __builtin_amdgcn_mfma_f32_16x16x32_bf16(wf[dt], bv2, acc[rt][dt], 0, 0, 0);
            }
        }
    }

    #pragma unroll
    for (int rt = 0; rt < 2; ++rt) {
        if (!ok[rt]) continue;
        #pragma unroll
        for (int dt = 0; dt < 8; ++dt) {
            const float4 bz = *(const float4*)(beff + dt * 16 + khi * 4);
            float v0 = fmaxf(acc[rt][dt][0] + bz.x, 0.f);
            float v1 = fmaxf(acc[rt][dt][1] + bz.y, 0.f);
            float v2 = fmaxf(acc[rt][dt][2] + bz.z, 0.f);
            float v3 = fmaxf(acc[rt][dt][3] + bz.w, 0.f);
            if constexpr (OUTF32) {
                *(float4*)(Yf + (size_t)row[rt] * 128 + dt * 16 + khi * 4) = make_float4(v0, v1, v2, v3);
            } else {
                uint2 pk;
                pk.x = (uint)f2bf(v0) | ((uint)f2bf(v1) << 16);
                pk.y = (uint)f2bf(v2) | ((uint)f2bf(v3) << 16);
                *(uint2*)(Yb + (size_t)row[rt] * 128 + dt * 16 + khi * 4) = pk;
            }
        }
    }
}

// ---------------- segmented mean over sorted runs; 64 lanes per node ----------------
template<bool FIRST>
__global__ __launch_bounds__(256) void reduce_half(
    const uint* __restrict__ Y2, const int* __restrict__ off,
    float2* __restrict__ hacc, uint* __restrict__ h2, uint* __restrict__ fh2,
    int fhsel, int N) {
    int lane = threadIdx.x & 63;
    int nn = blockIdx.x * 4 + (threadIdx.x >> 6);
    if (nn >= N) return;
    int a = off[nn], b = off[nn + 1];
    float s0 = 0.f, s1 = 0.f;
    for (int r = a; r < b; ++r) {
        uint u = Y2[(size_t)r * 64 + lane];
        s0 += bf2f(u & 0xffffu);
        s1 += bf2f(u >> 16);
    }
    float inv = 0.5f / fmaxf((float)(b - a), 1.f);
    s0 *= inv; s1 *= inv;
    if constexpr (FIRST) {
        hacc[(size_t)nn * 64 + lane] = make_float2(s0, s1);
    } else {
        float2 p = hacc[(size_t)nn * 64 + lane];
        float v0 = p.x + s0, v1 = p.y + s1;
        uint pk = (uint)f2bf(v0) | ((uint)f2bf(v1) << 16);
        h2[(size_t)nn * 64 + lane] = pk;
        if (fhsel >= 0) fh2[(size_t)nn * 128 + fhsel * 64 + lane] = pk;
    }
}

// ---------------- launch ----------------
extern "C" void kernel_launch(void* const* d_in, const int* in_sizes, int n_in,
                              void* d_out, int out_size, void* d_ws, size_t ws_size,
                              hipStream_t stream) {
    const float* win_f  = (const float*)d_in[0];
    const float* loss_f = (const float*)d_in[1];
    struct BP { const float *g, *b, *W, *bias; };
    auto bp = [&](int i) { return BP{ (const float*)d_in[i], (const float*)d_in[i+1],
                                      (const float*)d_in[i+2], (const float*)d_in[i+3] }; };
    BP wi = bp(2), li = bp(6), srcp = bp(10), dstp = bp(14), wl = bp(18), ll = bp(22), outp = bp(26);
    const int* win_src  = (const int*)d_in[30];
    const int* win_dst  = (const int*)d_in[31];
    const int* loss_src = (const int*)d_in[32];
    const int* loss_dst = (const int*)d_in[33];
    const int E = in_sizes[30];
    const int N = out_size / 128;
    (void)n_in;

    char* base = (char*)d_ws;
    size_t off_b = 0;
    auto alloc = [&](size_t bytes) {
        size_t cur = off_b;
        off_b += (bytes + 255) & ~(size_t)255;
        return (void*)(base + cur);
    };
    ushort* Y    = (ushort*)alloc((size_t)E * 128 * 2);
    float2* hacc = (float2*)alloc((size_t)N * 64 * 8);
    ushort* h    = (ushort*)alloc((size_t)N * 128 * 2);
    ushort* hu   = (ushort*)alloc((size_t)N * 128 * 2);
    ushort* hv   = (ushort*)alloc((size_t)N * 128 * 2);
    ushort* fh   = (ushort*)alloc((size_t)N * 256 * 2);
    int* cntw  = (int*)alloc((size_t)N * 4);
    int* cntl  = (int*)alloc((size_t)N * 4);
    int* offw  = (int*)alloc((size_t)(N + 1) * 4);
    int* offl  = (int*)alloc((size_t)(N + 1) * 4);
    int* curw  = (int*)alloc((size_t)N * 4);
    int* curl  = (int*)alloc((size_t)N * 4);
    int* permw = (int*)alloc((size_t)E * 4);
    int* ssrcw = (int*)alloc((size_t)E * 4);
    int* sdstw = (int*)alloc((size_t)E * 4);
    int* perml = (int*)alloc((size_t)E * 4);
    int* ssrcl = (int*)alloc((size_t)E * 4);
    int* sdstl = (int*)alloc((size_t)E * 4);
    float* psum = (float*)alloc((size_t)NBLK_STATS * 256 * 4);
    float* psq  = (float*)alloc((size_t)NBLK_STATS * 256 * 4);
    ushort* Wp  = (ushort*)alloc((size_t)256 * 128 * 2);
    float* beff = (float*)alloc(128 * 4);
    if (off_b > ws_size) return;

    const int gE = (E + 127) / 128;
    const int gN = (N + 127) / 128;
    const int gR = (N + 3) / 4;

    // phase 0: counting sort per etype
    hipMemsetAsync(cntw, 0, (size_t)N * 4, stream);
    hipMemsetAsync(cntl, 0, (size_t)N * 4, stream);
    hist_kernel<<<1024, 256, 0, stream>>>(win_dst,  E, cntw);
    hist_kernel<<<1024, 256, 0, stream>>>(loss_dst, E, cntl);
    scan_kernel<<<1, 256, 0, stream>>>(cntw, N, offw, curw);
    scan_kernel<<<1, 256, 0, stream>>>(cntl, N, offl, curl);
    scatter_kernel<<<1024, 256, 0, stream>>>(win_src,  win_dst,  E, curw, permw, ssrcw, sdstw);
    scatter_kernel<<<1024, 256, 0, stream>>>(loss_src, loss_dst, E, curl, perml, ssrcl, sdstl);

    // initial edge blocks
    colstats_f32_128<<<NBLK_STATS, 256, 0, stream>>>(win_f, E, psum, psq);
    finalize_fold<<<1, 256, 0, stream>>>(psum, psq, E, 128, wi.W, wi.bias, wi.g, wi.b, Wp, beff);
    gemm_mfma<4, false, true, false><<<gE, 256, 0, stream>>>(
        nullptr, nullptr, win_f, permw, nullptr, Wp, beff, Y, nullptr, E);
    reduce_half<true><<<gR, 256, 0, stream>>>((const uint*)Y, offw, hacc, nullptr, nullptr, -1, N);

    colstats_f32_128<<<NBLK_STATS, 256, 0, stream>>>(loss_f, E, psum, psq);
    finalize_fold<<<1, 256, 0, stream>>>(psum, psq, E, 128, li.W, li.bias, li.g, li.b, Wp, beff);
    gemm_mfma<4, false, true, false><<<gE, 256, 0, stream>>>(
        nullptr, nullptr, loss_f, perml, nullptr, Wp, beff, Y, nullptr, E);
    reduce_half<false><<<gR, 256, 0, stream>>>((const uint*)Y, offl, hacc, (uint*)h, (uint*)fh, 0, N);

    for (int it = 0; it < 3; ++it) {
        colstats_bf16_direct<128><<<NBLK_STATS, 256, 0, stream>>>(h, N, psum, psq);
        finalize_fold<<<1, 256, 0, stream>>>(psum, psq, N, 128, srcp.W, srcp.bias, srcp.g, srcp.b, Wp, beff);
        gemm_mfma<4, false, false, false><<<gN, 256, 0, stream>>>(
            h, nullptr, nullptr, nullptr, nullptr, Wp, beff, hu, nullptr, N);
        finalize_fold<<<1, 256, 0, stream>>>(psum, psq, N, 128, dstp.W, dstp.bias, dstp.g, dstp.b, Wp, beff);
        gemm_mfma<4, false, false, false><<<gN, 256, 0, stream>>>(
            h, nullptr, nullptr, nullptr, nullptr, Wp, beff, hv, nullptr, N);

        colstats_bf16_gather<<<NBLK_STATS, 256, 0, stream>>>(hu, hv, win_src, win_dst, E, psum, psq);
        finalize_fold<<<1, 256, 0, stream>>>(psum, psq, E, 128, wl.W, wl.bias, wl.g, wl.b, Wp, beff);
        gemm_mfma<4, true, false, false><<<gE, 256, 0, stream>>>(
            hu, hv, nullptr, ssrcw, sdstw, Wp, beff, Y, nullptr, E);
        reduce_half<true><<<gR, 256, 0, stream>>>((const uint*)Y, offw, hacc, nullptr, nullptr, -1, N);

        colstats_bf16_gather<<<NBLK_STATS, 256, 0, stream>>>(hu, hv, loss_src, loss_dst, E, psum, psq);
        finalize_fold<<<1, 256, 0, stream>>>(psum, psq, E, 128, ll.W, ll.bias, ll.g, ll.b, Wp, beff);
        gemm_mfma<4, true, false, false><<<gE, 256, 0, stream>>>(
            hu, hv, nullptr, ssrcl, sdstl, Wp, beff, Y, nullptr, E);
        reduce_half<false><<<gR, 256, 0, stream>>>((const uint*)Y, offl, hacc, (uint*)h, (uint*)fh,
                                                   (it == 2) ? 1 : -1, N);
    }

    colstats_bf16_direct<256><<<NBLK_STATS, 256, 0, stream>>>(fh, N, psum, psq);
    finalize_fold<<<1, 256, 0, stream>>>(psum, psq, N, 256, outp.W, outp.bias, outp.g, outp.b, Wp, beff);
    gemm_mfma<8, false, false, true><<<gN, 256, 0, stream>>>(
        fh, nullptr, nullptr, nullptr, nullptr, Wp, beff, nullptr, (float*)d_out, N);
}